// Round 14
// baseline (316.770 us; speedup 1.0000x reference)
//
#include <hip/hip_runtime.h>
#include <math.h>
#include <stdint.h>

#define B_ 2
#define L_ 2048
#define D_ 2048
#define H_ 32
#define HKV_ 8
#define HD_ 64
#define EPS_ 1e-5f

typedef _Float16 half_t;
typedef __attribute__((ext_vector_type(8))) _Float16 half8_t;
typedef __attribute__((ext_vector_type(4))) _Float16 half4_t;
typedef __attribute__((ext_vector_type(4))) float float4_t;

// global_load_lds width=16: per-lane global src, LDS dest = wave-uniform base + lane*16
typedef const __attribute__((address_space(1))) uint32_t glb_u32;
typedef __attribute__((address_space(3))) uint32_t lds_u32;
#define GLOAD_LDS16(gp, lp) \
  __builtin_amdgcn_global_load_lds((glb_u32*)(gp), (lds_u32*)(lp), 16, 0, 0)

__device__ __forceinline__ float4_t fmax4(float4_t a, float4_t b) {
  float4_t r;
  r[0] = fmaxf(a[0], b[0]); r[1] = fmaxf(a[1], b[1]);
  r[2] = fmaxf(a[2], b[2]); r[3] = fmaxf(a[3], b[3]);
  return r;
}

// pack two f32 -> one u32 of 2xfp16 (RTZ), via the builtin's native type
__device__ __forceinline__ uint32_t pk_f16(float a, float b) {
  auto p = __builtin_amdgcn_cvt_pkrtz(a, b);   // __fp16 ext_vector_type(2)
  return __builtin_bit_cast(uint32_t, p);
}

// ---------------------------------------------------------------------------
// prep_all: fused x->fp16 convert + 4 weight transpose/converts (one launch).
// ---------------------------------------------------------------------------
__global__ __launch_bounds__(256) void prep_all(
    const float* __restrict__ x,
    const float* __restrict__ Wq, const float* __restrict__ Wk,
    const float* __restrict__ Wv, const float* __restrict__ Wo,
    half_t* __restrict__ xh,
    half_t* __restrict__ Wqt, half_t* __restrict__ Wkt,
    half_t* __restrict__ Wvt, half_t* __restrict__ Wot)
{
  __shared__ float tile[64][65];
  const int t = threadIdx.x;
  int id = blockIdx.x;

  if (id < 4096) {           // x convert: 8 elems/thread
    size_t i = ((size_t)id * 256 + t) * 8;
    float4 v0 = *(const float4*)&x[i];
    float4 v1 = *(const float4*)&x[i + 4];
    half8_t h;
    h[0] = (half_t)v0.x; h[1] = (half_t)v0.y; h[2] = (half_t)v0.z; h[3] = (half_t)v0.w;
    h[4] = (half_t)v1.x; h[5] = (half_t)v1.y; h[6] = (half_t)v1.z; h[7] = (half_t)v1.w;
    *(half8_t*)&xh[i] = h;
    return;
  }
  id -= 4096;
  const float* W; half_t* Wt; int N;
  if (id < 1024)      { W = Wq; Wt = Wqt; N = 2048; }
  else if (id < 1280) { id -= 1024; W = Wk; Wt = Wkt; N = 512; }
  else if (id < 1536) { id -= 1280; W = Wv; Wt = Wvt; N = 512; }
  else                { id -= 1536; W = Wo; Wt = Wot; N = 2048; }
  const int K = 2048;
  int tk = id & 31, tn = id >> 5;
  int k0 = tk * 64, n0 = tn * 64;

  int rr = t >> 6, cc = t & 63;
#pragma unroll
  for (int i = 0; i < 16; i++)
    tile[rr + i * 4][cc] = W[(size_t)(k0 + rr + i * 4) * N + n0 + cc];
  __syncthreads();

  int rn = t >> 2, q4 = (t & 3) * 16;
  half8_t h0, h1;
#pragma unroll
  for (int u = 0; u < 8; u++) h0[u] = (half_t)tile[q4 + u][rn];
#pragma unroll
  for (int u = 0; u < 8; u++) h1[u] = (half_t)tile[q4 + 8 + u][rn];
  *(half8_t*)&Wt[(size_t)(n0 + rn) * K + k0 + q4]     = h0;
  *(half8_t*)&Wt[(size_t)(n0 + rn) * K + k0 + q4 + 8] = h1;
}

// ---------------------------------------------------------------------------
// fp16 MFMA GEMM: C[row0:+128][col0:+128] = A[M][K] @ Bt[N][K]^T
// m97-style staging: global_load_lds width=16 into LINEAR [128][32] LDS.
// tv=true (v-blocks): write C DIRECTLY TRANSPOSED into vt[(b*8+kvh)*64+d][tok].
// ---------------------------------------------------------------------------
template <typename CT>
__device__ __forceinline__ void gemm_tile_f16(
    const half_t* __restrict__ A, const half_t* __restrict__ Bt,
    CT* __restrict__ C, int K, int ldc, int row0, int col0,
    bool tv, half_t* __restrict__ vtp)
{
  __shared__ __align__(16) half_t As[128 * 32];   // row-major, 64B rows
  __shared__ __align__(16) half_t Bs[128 * 32];
  const int t    = threadIdx.x;
  const int lane = t & 63;
  const int w    = t >> 6;
  const int quad = lane >> 4, c = lane & 15;
  const int wm = (w >> 1) * 64, wn = (w & 1) * 64;

  float4_t acc[4][4];
#pragma unroll
  for (int i = 0; i < 4; i++)
#pragma unroll
    for (int j = 0; j < 4; j++) acc[i][j] = (float4_t){0.f, 0.f, 0.f, 0.f};

  // staging map: wave w covers rows w*32..w*32+31 in 2 calls of 16 rows.
  const int srow = w * 32 + (lane >> 2);
  const int scol = (lane & 3) * 8;                 // halfs
  const half_t* Ag0 = A  + (size_t)(row0 + srow) * K + scol;
  const half_t* Ag1 = Ag0 + (size_t)16 * K;
  const half_t* Bg0 = Bt + (size_t)(col0 + srow) * K + scol;
  const half_t* Bg1 = Bg0 + (size_t)16 * K;
  half_t* As_w0 = &As[(w * 32) * 32];
  half_t* As_w1 = &As[(w * 32 + 16) * 32];
  half_t* Bs_w0 = &Bs[(w * 32) * 32];
  half_t* Bs_w1 = &Bs[(w * 32 + 16) * 32];

  for (int k0 = 0; k0 < K; k0 += 32) {
    __syncthreads();                       // prior tile's ds_reads done
    GLOAD_LDS16(Ag0 + k0, As_w0);
    GLOAD_LDS16(Ag1 + k0, As_w1);
    GLOAD_LDS16(Bg0 + k0, Bs_w0);
    GLOAD_LDS16(Bg1 + k0, Bs_w1);
    __syncthreads();                       // compiler drains vmcnt(0) here

    half8_t af[4], bf[4];
#pragma unroll
    for (int i = 0; i < 4; i++)
      af[i] = *(const half8_t*)&As[(wm + i * 16 + c) * 32 + quad * 8];
#pragma unroll
    for (int j = 0; j < 4; j++)
      bf[j] = *(const half8_t*)&Bs[(wn + j * 16 + c) * 32 + quad * 8];
#pragma unroll
    for (int i = 0; i < 4; i++)
#pragma unroll
      for (int j = 0; j < 4; j++)
        acc[i][j] = __builtin_amdgcn_mfma_f32_16x16x32_f16(af[i], bf[j], acc[i][j], 0, 0, 0);
  }

  if (tv) {
    // v path: col = (col0+wn) + j*16 + c, (col0+wn) % 64 == 0
    const int kvq = (col0 + wn) >> 6;                // kv head 0..7
#pragma unroll
    for (int i = 0; i < 4; i++) {
      int row = row0 + wm + i * 16 + quad * 4;       // token r=0 of this group
      int bb  = row >> 11;
      int tok = row & (L_ - 1);
      half_t* vbase = vtp + (((size_t)bb * HKV_ + kvq) * HD_ + c) * L_ + tok;
#pragma unroll
      for (int j = 0; j < 4; j++) {
        half4_t h4;
#pragma unroll
        for (int r = 0; r < 4; r++) h4[r] = (half_t)acc[i][j][r];
        *(half4_t*)(vbase + (size_t)(j * 16) * L_) = h4;
      }
    }
  } else {
#pragma unroll
    for (int i = 0; i < 4; i++)
#pragma unroll
      for (int r = 0; r < 4; r++) {
        CT* Cp = C + (size_t)(row0 + wm + i * 16 + quad * 4 + r) * ldc + col0 + wn + c;
#pragma unroll
        for (int j = 0; j < 4; j++)
          Cp[j * 16] = (CT)acc[i][j][r];
      }
  }
}

__global__ __launch_bounds__(256) void qkv_gemm_h(
    const half_t* __restrict__ xh,
    const half_t* __restrict__ Wqt, const half_t* __restrict__ Wkt,
    const half_t* __restrict__ Wvt,
    half_t* __restrict__ qh, half_t* __restrict__ kh, half_t* __restrict__ vt)
{
  // XCD 2x4-chunk swizzle (bijective, 768 = 8 * 96): A/B-validated −10 µs.
  int lin = (int)blockIdx.y * 24 + (int)blockIdx.x;
  int xcd = lin & 7, idx = lin >> 3;           // idx in [0,96)
  int cy = xcd >> 2, cx = xcd & 3;
  int by = cy * 16 + idx / 6;
  int bx = cx * 6 + idx % 6;

  const half_t* Bt; half_t* C; int ldc, col0; bool tv = false;
  if (bx < 16)      { Bt = Wqt; C = qh; ldc = H_ * HD_;   col0 = bx * 128; }
  else if (bx < 20) { Bt = Wkt; C = kh; ldc = HKV_ * HD_; col0 = (bx - 16) * 128; }
  else              { Bt = Wvt; C = vt; ldc = HKV_ * HD_; col0 = (bx - 20) * 128;
                      tv = true; }
  gemm_tile_f16<half_t>(xh, Bt, C, D_, ldc, by * 128, col0, tv, vt);
}

__global__ __launch_bounds__(256) void out_gemm_h(
    const half_t* __restrict__ attn, const half_t* __restrict__ Wot,
    float* __restrict__ out)
{
  // XCD 4x2-chunk swizzle (bijective, 512 = 8 * 64): each XCD owns 8x8.
  int lin = (int)blockIdx.y * 16 + (int)blockIdx.x;
  int xcd = lin & 7, idx = lin >> 3;           // idx in [0,64)
  int cy = xcd >> 1, cx = xcd & 1;
  int by = cy * 8 + idx / 8;
  int bx = cx * 8 + idx % 8;
  gemm_tile_f16<float>(attn, Wot, out, H_ * HD_, D_, by * 128, bx * 128,
                       false, nullptr);
}

// ---------------------------------------------------------------------------
// mid: blocks 0..255 build the RoPE trig table (into dead-after-qkv Wqt
// region; consumed by flash's fused q-norm); blocks 256.. do k-norm+RoPE
// (inline trig — bitwise-identical expressions; r13-verified path).
// No intra-kernel ordering needed (k-norm doesn't read the table).
// ---------------------------------------------------------------------------
__device__ __forceinline__ void norm_rope_row(
    half_t* __restrict__ buf, float wv, int row, int nheads, int lognh,
    int lane, float oscale, float cv, float sv)
{
  int head  = row & (nheads - 1);
  int token = row >> lognh;

  size_t idx = (size_t)token * (nheads * HD_) + head * HD_ + lane;
  float x = (float)buf[idx];

  float ss = x * x;
#pragma unroll
  for (int off = 32; off; off >>= 1) ss += __shfl_xor(ss, off);
  float xn = x * rsqrtf(ss * (1.0f / HD_) + EPS_) * wv;

  float partner = __shfl_xor(xn, 32);
  float res = (lane < 32) ? (xn * cv - partner * sv) : (xn * cv + partner * sv);
  buf[idx] = (half_t)(res * oscale);
}

__global__ __launch_bounds__(256) void mid(
    half_t* __restrict__ kh, const float* __restrict__ kw,
    float* __restrict__ ct, float* __restrict__ st)
{
  const int t = threadIdx.x;
  int id = blockIdx.x;

  if (id < 256) {            // trig table: 65536 entries = 2048 pos x 32
    int e = id * 256 + t;
    int l = e >> 5, fi = e & 31;
    float inv_freq = exp2f((float)fi * -0.622862853f);   // 1e6^(-2fi/64)
    float ang = (float)l * inv_freq;
    ct[e] = cosf(ang);
    st[e] = sinf(ang);
    return;
  }
  id -= 256;                 // k norm: 2048 blk x 4 waves x 4 rows = 32768 rows
  const int lane = t & 63;
  const int wv   = t >> 6;
  int fi = lane & 31;
  float inv_freq = exp2f((float)fi * -0.622862853f);
  int row0  = (id * 4 + wv) * 4;
  int token = row0 >> 3;                 // all 4 rows share one token
  int l     = token & (L_ - 1);          // RoPE position (batch masked out)
  float ang = (float)l * inv_freq;
  float cvv = cosf(ang), svv = sinf(ang);
  float wk  = kw[lane];
#pragma unroll
  for (int u = 0; u < 4; u++)
    norm_rope_row(kh, wk, row0 + u, HKV_, 3, lane, 1.0f, cvv, svv);
}

// ---------------------------------------------------------------------------
// MFMA flash attention (round-11 body) + FUSED q-norm/RoPE on the Q-load:
// lane (quad,c) holds dims {q8+j} and {32+q8+j} of q-row wq0+c — RoPE pairs
// are in-lane (qf0[j]<->qf1[j], same freq index), sum-of-squares needs only
// shfl_xor(16)+shfl_xor(32) across the 4 quads. Runs once per pass, amortized
// over ~36 tiles. Deletes postproc's q-section + 32 MB qh round-trip.
// ---------------------------------------------------------------------------
__global__ __launch_bounds__(512) void flash_mfma2(
    const half_t* __restrict__ Qh, const half_t* __restrict__ Kh,
    const half_t* __restrict__ Vt, half_t* __restrict__ Oa,
    const float* __restrict__ qw,
    const float* __restrict__ ct, const float* __restrict__ st)
{
  __shared__ __align__(16) half_t Ks[64][72];   // [k-token][d]
  __shared__ __align__(16) half_t Vs[64][72];   // [d][k-token]
  __shared__ __align__(16) half_t Ps[128][72];  // [q-local][k-local]
  __shared__ __align__(16) float  Ab[128];      // per-row alpha broadcast

  const int t    = threadIdx.x;
  const int w    = t >> 6;          // 0..7
  const int lane = t & 63;
  const int quad = lane >> 4;
  const int c    = lane & 15;
  const int h = blockIdx.y, b = blockIdx.z;
  const int kvh = h >> 2;

  const half_t* kbase = Kh + (size_t)(b * L_) * (HKV_ * HD_) + kvh * HD_;
  const half_t* vbase = Vt + (size_t)((b * HKV_ + kvh) * HD_) * L_;
  const int sr = t >> 3;            // 0..63
  const int su = (t & 7) * 8;       // 0..56 (halfs)

  half8_t ones;
#pragma unroll
  for (int u = 0; u < 8; u++) ones[u] = (half_t)1.0f;

  for (int pass = 0; pass < 2; pass++) {
    const int qb  = pass ? (15 - (int)blockIdx.x) : (int)blockIdx.x;
    const int q0  = qb * 128;
    const int wq0 = q0 + w * 16;    // this wave's first q row

    // Q fragments: fused RMS-norm + RoPE (table) on load
    half8_t qf0, qf1;
    {
      const half_t* qp = Qh + ((size_t)(b * L_ + wq0 + c)) * (H_ * HD_) + h * HD_;
      half8_t r0 = *(const half8_t*)&qp[quad * 8];
      half8_t r1 = *(const half8_t*)&qp[32 + quad * 8];
      float x1[8], x2[8];
      float ss = 0.f;
#pragma unroll
      for (int j = 0; j < 8; j++) {
        x1[j] = (float)r0[j]; x2[j] = (float)r1[j];
        ss += x1[j] * x1[j] + x2[j] * x2[j];
      }
      ss += __shfl_xor(ss, 16);
      ss += __shfl_xor(ss, 32);
      float rn = rsqrtf(ss * (1.0f / HD_) + EPS_);
      const int l = wq0 + c;                 // q position in [0, 2048)
      float4 c0 = *(const float4*)&ct[l * 32 + quad * 8];
      float4 c1 = *(const float4*)&ct[l * 32 + quad * 8 + 4];
      float4 s0 = *(const float4*)&st[l * 32 + quad * 8];
      float4 s1 = *(const float4*)&st[l * 32 + quad * 8 + 4];
      float4 w0 = *(const float4*)&qw[quad * 8];
      float4 w1 = *(const float4*)&qw[quad * 8 + 4];
      float4 w2 = *(const float4*)&qw[32 + quad * 8];
      float4 w3 = *(const float4*)&qw[32 + quad * 8 + 4];
      const float cs[8] = {c0.x, c0.y, c0.z, c0.w, c1.x, c1.y, c1.z, c1.w};
      const float sn[8] = {s0.x, s0.y, s0.z, s0.w, s1.x, s1.y, s1.z, s1.w};
      const float wa[8] = {w0.x, w0.y, w0.z, w0.w, w1.x, w1.y, w1.z, w1.w};
      const float wb[8] = {w2.x, w2.y, w2.z, w2.w, w3.x, w3.y, w3.z, w3.w};
#pragma unroll
      for (int j = 0; j < 8; j++) {
        float xa = x1[j] * rn * wa[j];
        float xb = x2[j] * rn * wb[j];
        qf0[j] = (half_t)((xa * cs[j] - xb * sn[j]) * 0.180336880f);
        qf1[j] = (half_t)((xb * cs[j] + xa * sn[j]) * 0.180336880f);
      }
    }

    float4_t o[5];                  // o[0..3] = O, o[4] = l (row-sum via ones-MFMA)
#pragma unroll
    for (int dt = 0; dt < 5; dt++) o[dt] = (float4_t){0.f, 0.f, 0.f, 0.f};
    float mm = -__builtin_inff();

    // prefetch tile 0 (one 16B chunk per thread for each of K, V)
    half8_t kr, vr;
    kr = *(const half8_t*)(kbase + (size_t)sr * (HKV_ * HD_) + su);
    vr = *(const half8_t*)(vbase + (size_t)sr * L_ + su);

    const int last = (q0 + 127) >> 6;
    for (int kt = 0; kt <= last; kt++) {
      const int kk0 = kt * 64;
      __syncthreads();
      *(half8_t*)&Ks[sr][su] = kr;
      *(half8_t*)&Vs[sr][su] = vr;
      __syncthreads();
      if (kt < last) {   // prefetch next tile while computing this one
        kr = *(const half8_t*)(kbase + (size_t)(kk0 + 64 + sr) * (HKV_ * HD_) + su);
        vr = *(const half8_t*)(vbase + (size_t)sr * L_ + kk0 + 64 + su);
      }
      if (kk0 > wq0 + 15) continue;   // tile fully above diagonal for this wave

      // S^T[k][q] = K Q^T : A = K frag, B = Q frag
      float4_t S[4];
      __builtin_amdgcn_s_setprio(1);
#pragma unroll
      for (int tt = 0; tt < 4; tt++) {
        half8_t kf0 = *(const half8_t*)&Ks[tt * 16 + c][quad * 8];
        half8_t kf1 = *(const half8_t*)&Ks[tt * 16 + c][32 + quad * 8];
        float4_t s = (float4_t){0.f, 0.f, 0.f, 0.f};
        s = __builtin_amdgcn_mfma_f32_16x16x32_f16(kf0, qf0, s, 0, 0, 0);
        s = __builtin_amdgcn_mfma_f32_16x16x32_f16(kf1, qf1, s, 0, 0, 0);
        S[tt] = s;
      }
      __builtin_amdgcn_s_setprio(0);

      // causal mask (only near-diagonal tiles)
      if (kk0 + 63 > wq0) {
#pragma unroll
        for (int tt = 0; tt < 4; tt++) {
          int base = kk0 + tt * 16 + quad * 4 - (wq0 + c);
#pragma unroll
          for (int r = 0; r < 4; r++)
            if (base + r > 0) S[tt][r] = -__builtin_inff();
        }
      }

      // online softmax (exp2 domain), defer-max THR=8
      {
        float4_t m4 = fmax4(fmax4(S[0], S[1]), fmax4(S[2], S[3]));
        float mloc = fmaxf(fmaxf(m4[0], m4[1]), fmaxf(m4[2], m4[3]));
        mloc = fmaxf(mloc, __shfl_xor(mloc, 16));
        mloc = fmaxf(mloc, __shfl_xor(mloc, 32));
        if (__any(mloc > mm + 8.0f)) {       // wave-uniform rescale (rare)
          float mnew = fmaxf(mm, mloc);
          float al = exp2f(mm - mnew);
          mm = mnew;
          if (quad == 0) Ab[w * 16 + c] = al;
          float4_t av = *(const float4_t*)&Ab[w * 16 + quad * 4];
#pragma unroll
          for (int dt = 0; dt < 5; dt++)
#pragma unroll
            for (int r = 0; r < 4; r++) o[dt][r] *= av[r];
        }
#pragma unroll
        for (int tt = 0; tt < 4; tt++) {
#pragma unroll
          for (int r = 0; r < 4; r++) S[tt][r] = exp2f(S[tt][r] - mm);
          uint2 pw;
          pw.x = pk_f16(S[tt][0], S[tt][1]);
          pw.y = pk_f16(S[tt][2], S[tt][3]);
          *(uint2*)&Ps[w * 16 + c][tt * 16 + quad * 4] = pw;
        }
      }

      // O += P V ; l += P 1 (ones-MFMA)
      half8_t pf0 = *(const half8_t*)&Ps[w * 16 + c][quad * 8];
      half8_t pf1 = *(const half8_t*)&Ps[w * 16 + c][32 + quad * 8];
      __builtin_amdgcn_s_setprio(1);
      o[4] = __builtin_amdgcn_mfma_f32_16x16x32_f16(pf0, ones, o[4], 0, 0, 0);
      o[4] = __builtin_amdgcn_mfma_f32_16x16x32_f16(pf1, ones, o[4], 0, 0, 0);
#pragma unroll
      for (int dt = 0; dt < 4; dt++) {
        half8_t vf0 = *(const half8_t*)&Vs[dt * 16 + c][quad * 8];
        half8_t vf1 = *(const half8_t*)&Vs[dt * 16 + c][32 + quad * 8];
        o[dt] = __builtin_amdgcn_mfma_f32_16x16x32_f16(pf0, vf0, o[dt], 0, 0, 0);
        o[dt] = __builtin_amdgcn_mfma_f32_16x16x32_f16(pf1, vf1, o[dt], 0, 0, 0);
      }
      __builtin_amdgcn_s_setprio(0);
    }

    // epilogue: normalize by l (= o[4], same row layout), store
#pragma unroll
    for (int r = 0; r < 4; r++) {
      float inv = 1.0f / o[4][r];
      half_t* op = Oa + ((size_t)(b * L_ + wq0 + quad * 4 + r)) * (H_ * HD_)
                 + h * HD_ + c;
#pragma unroll
      for (int dt = 0; dt < 4; dt++)
        op[dt * 16] = (half_t)(o[dt][r] * inv);
    }
  }
}

// ---------------------------------------------------------------------------
extern "C" void kernel_launch(void* const* d_in, const int* in_sizes, int n_in,
                              void* d_out, int out_size, void* d_ws, size_t ws_size,
                              hipStream_t stream)
{
  const float* x  = (const float*)d_in[0];
  const float* Wq = (const float*)d_in[1];
  const float* Wk = (const float*)d_in[2];
  const float* Wv = (const float*)d_in[3];
  const float* Wo = (const float*)d_in[4];
  const float* qw = (const float*)d_in[5];
  const float* kw = (const float*)d_in[6];
  float* out = (float*)d_out;

  const size_t XN = (size_t)B_ * L_ * D_;          // 8M
  const size_t QN = (size_t)B_ * L_ * H_ * HD_;    // 8M
  const size_t KN = (size_t)B_ * L_ * HKV_ * HD_;  // 2M
  const size_t WQ = (size_t)D_ * H_ * HD_;         // 4M
  const size_t WK = (size_t)D_ * HKV_ * HD_;       // 1M

  half_t* p   = (half_t*)d_ws;
  half_t* xh  = p;  p += XN;   // reused as attn output
  half_t* Wqt = p;  p += WQ;
  half_t* Wkt = p;  p += WK;
  half_t* Wvt = p;  p += WK;
  half_t* Wot = p;  p += WQ;
  half_t* qh  = p;  p += QN;
  half_t* kh  = p;  p += KN;
  half_t* vt  = p;  p += KN;   // written DIRECTLY transposed by qkv_gemm_h
  half_t* attn = xh;           // xh dead after qkv_gemm_h

  // trig table overlays the Wqt region (dead after qkv_gemm_h); consumed by
  // flash's fused q-norm — Wqt not otherwise read after qkv.
  float* ct = (float*)Wqt;     // 65536 floats
  float* st = ct + 65536;      // 65536 floats (512KB total << 8MB region)

  // 0) fused conversions + weight transposes
  prep_all<<<6656, 256, 0, stream>>>(x, Wq, Wk, Wv, Wo, xh, Wqt, Wkt, Wvt, Wot);

  // 1) QKV projections (fp16 MFMA, global_load_lds staging, XCD swizzle;
  //    v written direct-transposed into vt; q/k written RAW — normed later)
  qkv_gemm_h<<<dim3(24, 32), 256, 0, stream>>>(xh, Wqt, Wkt, Wvt, qh, kh, vt);

  // 2) trig table (into dead Wqt region) + k-norm/RoPE, one launch
  mid<<<256 + 2048, 256, 0, stream>>>(kh, kw, ct, st);

  // 3) MFMA flash attention with fused q-norm/RoPE on Q-load
  flash_mfma2<<<dim3(8, H_, B_), 512, 0, stream>>>(qh, kh, vt, attn, qw, ct, st);

  // 4) output projection (fp16 MFMA, fp32 out, XCD swizzle)
  out_gemm_h<<<dim3(16, 32), 256, 0, stream>>>(attn, Wot, out);
}

// Round 15
// 315.295 us; speedup vs baseline: 1.0047x; 1.0047x over previous
//
#include <hip/hip_runtime.h>
#include <math.h>
#include <stdint.h>

#define B_ 2
#define L_ 2048
#define D_ 2048
#define H_ 32
#define HKV_ 8
#define HD_ 64
#define EPS_ 1e-5f

typedef _Float16 half_t;
typedef __attribute__((ext_vector_type(8))) _Float16 half8_t;
typedef __attribute__((ext_vector_type(4))) _Float16 half4_t;
typedef __attribute__((ext_vector_type(4))) float float4_t;

// global_load_lds width=16: per-lane global src, LDS dest = wave-uniform base + lane*16
typedef const __attribute__((address_space(1))) uint32_t glb_u32;
typedef __attribute__((address_space(3))) uint32_t lds_u32;
#define GLOAD_LDS16(gp, lp) \
  __builtin_amdgcn_global_load_lds((glb_u32*)(gp), (lds_u32*)(lp), 16, 0, 0)

__device__ __forceinline__ float4_t fmax4(float4_t a, float4_t b) {
  float4_t r;
  r[0] = fmaxf(a[0], b[0]); r[1] = fmaxf(a[1], b[1]);
  r[2] = fmaxf(a[2], b[2]); r[3] = fmaxf(a[3], b[3]);
  return r;
}

// pack two f32 -> one u32 of 2xfp16 (RTZ), via the builtin's native type
__device__ __forceinline__ uint32_t pk_f16(float a, float b) {
  auto p = __builtin_amdgcn_cvt_pkrtz(a, b);   // __fp16 ext_vector_type(2)
  return __builtin_bit_cast(uint32_t, p);
}

// ---------------------------------------------------------------------------
// prep_all: fused x->fp16 convert + 4 weight transpose/converts (one launch).
// ---------------------------------------------------------------------------
__global__ __launch_bounds__(256) void prep_all(
    const float* __restrict__ x,
    const float* __restrict__ Wq, const float* __restrict__ Wk,
    const float* __restrict__ Wv, const float* __restrict__ Wo,
    half_t* __restrict__ xh,
    half_t* __restrict__ Wqt, half_t* __restrict__ Wkt,
    half_t* __restrict__ Wvt, half_t* __restrict__ Wot)
{
  __shared__ float tile[64][65];
  const int t = threadIdx.x;
  int id = blockIdx.x;

  if (id < 4096) {           // x convert: 8 elems/thread
    size_t i = ((size_t)id * 256 + t) * 8;
    float4 v0 = *(const float4*)&x[i];
    float4 v1 = *(const float4*)&x[i + 4];
    half8_t h;
    h[0] = (half_t)v0.x; h[1] = (half_t)v0.y; h[2] = (half_t)v0.z; h[3] = (half_t)v0.w;
    h[4] = (half_t)v1.x; h[5] = (half_t)v1.y; h[6] = (half_t)v1.z; h[7] = (half_t)v1.w;
    *(half8_t*)&xh[i] = h;
    return;
  }
  id -= 4096;
  const float* W; half_t* Wt; int N;
  if (id < 1024)      { W = Wq; Wt = Wqt; N = 2048; }
  else if (id < 1280) { id -= 1024; W = Wk; Wt = Wkt; N = 512; }
  else if (id < 1536) { id -= 1280; W = Wv; Wt = Wvt; N = 512; }
  else                { id -= 1536; W = Wo; Wt = Wot; N = 2048; }
  const int K = 2048;
  int tk = id & 31, tn = id >> 5;
  int k0 = tk * 64, n0 = tn * 64;

  int rr = t >> 6, cc = t & 63;
#pragma unroll
  for (int i = 0; i < 16; i++)
    tile[rr + i * 4][cc] = W[(size_t)(k0 + rr + i * 4) * N + n0 + cc];
  __syncthreads();

  int rn = t >> 2, q4 = (t & 3) * 16;
  half8_t h0, h1;
#pragma unroll
  for (int u = 0; u < 8; u++) h0[u] = (half_t)tile[q4 + u][rn];
#pragma unroll
  for (int u = 0; u < 8; u++) h1[u] = (half_t)tile[q4 + 8 + u][rn];
  *(half8_t*)&Wt[(size_t)(n0 + rn) * K + k0 + q4]     = h0;
  *(half8_t*)&Wt[(size_t)(n0 + rn) * K + k0 + q4 + 8] = h1;
}

// ---------------------------------------------------------------------------
// fp16 MFMA GEMM: C[row0:+128][col0:+128] = A[M][K] @ Bt[N][K]^T
// ROUND-15 CHANGE: T3-minimum 2-phase double-buffered pipeline (one barrier
// per K-step; stage tile i+1 BEFORE compute of tile i; the compiler's
// vmcnt(0)+lgkmcnt(0) drain lands at the single barrier). Race audit:
// write buf[X]@iter i+1 vs reads buf[X]@iter i separated by that barrier;
// reads buf[Y] follow the barrier that drained Y's global_load_lds.
// tv=true (v-blocks): write C DIRECTLY TRANSPOSED into vt[(b*8+kvh)*64+d][tok].
// ---------------------------------------------------------------------------
template <typename CT>
__device__ __forceinline__ void gemm_tile_f16(
    const half_t* __restrict__ A, const half_t* __restrict__ Bt,
    CT* __restrict__ C, int K, int ldc, int row0, int col0,
    bool tv, half_t* __restrict__ vtp)
{
  __shared__ __align__(16) half_t As[2][128 * 32];   // double-buffered
  __shared__ __align__(16) half_t Bs[2][128 * 32];
  const int t    = threadIdx.x;
  const int lane = t & 63;
  const int w    = t >> 6;
  const int quad = lane >> 4, c = lane & 15;
  const int wm = (w >> 1) * 64, wn = (w & 1) * 64;

  float4_t acc[4][4];
#pragma unroll
  for (int i = 0; i < 4; i++)
#pragma unroll
    for (int j = 0; j < 4; j++) acc[i][j] = (float4_t){0.f, 0.f, 0.f, 0.f};

  // staging map: wave w covers rows w*32..w*32+31 in 2 calls of 16 rows.
  const int srow = w * 32 + (lane >> 2);
  const int scol = (lane & 3) * 8;                 // halfs
  const half_t* Ag0 = A  + (size_t)(row0 + srow) * K + scol;
  const half_t* Ag1 = Ag0 + (size_t)16 * K;
  const half_t* Bg0 = Bt + (size_t)(col0 + srow) * K + scol;
  const half_t* Bg1 = Bg0 + (size_t)16 * K;
  const int wb0 = (w * 32) * 32;        // wave LDS write base (halfs)
  const int wb1 = (w * 32 + 16) * 32;

  // prologue: stage tile 0 into buf 0; barrier drains vmcnt(0)
  GLOAD_LDS16(Ag0, &As[0][wb0]);
  GLOAD_LDS16(Ag1, &As[0][wb1]);
  GLOAD_LDS16(Bg0, &Bs[0][wb0]);
  GLOAD_LDS16(Bg1, &Bs[0][wb1]);
  __syncthreads();

  int cur = 0;
  for (int k0 = 0; k0 < K; k0 += 32) {
    if (k0 + 32 < K) {                   // stage NEXT tile into other buffer
      GLOAD_LDS16(Ag0 + k0 + 32, &As[cur ^ 1][wb0]);
      GLOAD_LDS16(Ag1 + k0 + 32, &As[cur ^ 1][wb1]);
      GLOAD_LDS16(Bg0 + k0 + 32, &Bs[cur ^ 1][wb0]);
      GLOAD_LDS16(Bg1 + k0 + 32, &Bs[cur ^ 1][wb1]);
    }

    half8_t af[4], bf[4];
#pragma unroll
    for (int i = 0; i < 4; i++)
      af[i] = *(const half8_t*)&As[cur][(wm + i * 16 + c) * 32 + quad * 8];
#pragma unroll
    for (int j = 0; j < 4; j++)
      bf[j] = *(const half8_t*)&Bs[cur][(wn + j * 16 + c) * 32 + quad * 8];
#pragma unroll
    for (int i = 0; i < 4; i++)
#pragma unroll
      for (int j = 0; j < 4; j++)
        acc[i][j] = __builtin_amdgcn_mfma_f32_16x16x32_f16(af[i], bf[j], acc[i][j], 0, 0, 0);

    __syncthreads();                     // drains vmcnt(0)+lgkmcnt(0)
    cur ^= 1;
  }

  if (tv) {
    // v path: col = (col0+wn) + j*16 + c, (col0+wn) % 64 == 0
    const int kvq = (col0 + wn) >> 6;                // kv head 0..7
#pragma unroll
    for (int i = 0; i < 4; i++) {
      int row = row0 + wm + i * 16 + quad * 4;       // token r=0 of this group
      int bb  = row >> 11;
      int tok = row & (L_ - 1);
      half_t* vbase = vtp + (((size_t)bb * HKV_ + kvq) * HD_ + c) * L_ + tok;
#pragma unroll
      for (int j = 0; j < 4; j++) {
        half4_t h4;
#pragma unroll
        for (int r = 0; r < 4; r++) h4[r] = (half_t)acc[i][j][r];
        *(half4_t*)(vbase + (size_t)(j * 16) * L_) = h4;
      }
    }
  } else {
#pragma unroll
    for (int i = 0; i < 4; i++)
#pragma unroll
      for (int r = 0; r < 4; r++) {
        CT* Cp = C + (size_t)(row0 + wm + i * 16 + quad * 4 + r) * ldc + col0 + wn + c;
#pragma unroll
        for (int j = 0; j < 4; j++)
          Cp[j * 16] = (CT)acc[i][j][r];
      }
  }
}

__global__ __launch_bounds__(256) void qkv_gemm_h(
    const half_t* __restrict__ xh,
    const half_t* __restrict__ Wqt, const half_t* __restrict__ Wkt,
    const half_t* __restrict__ Wvt,
    half_t* __restrict__ qh, half_t* __restrict__ kh, half_t* __restrict__ vt)
{
  // XCD 2x4-chunk swizzle (bijective, 768 = 8 * 96): A/B-validated −10 µs.
  int lin = (int)blockIdx.y * 24 + (int)blockIdx.x;
  int xcd = lin & 7, idx = lin >> 3;           // idx in [0,96)
  int cy = xcd >> 2, cx = xcd & 3;
  int by = cy * 16 + idx / 6;
  int bx = cx * 6 + idx % 6;

  const half_t* Bt; half_t* C; int ldc, col0; bool tv = false;
  if (bx < 16)      { Bt = Wqt; C = qh; ldc = H_ * HD_;   col0 = bx * 128; }
  else if (bx < 20) { Bt = Wkt; C = kh; ldc = HKV_ * HD_; col0 = (bx - 16) * 128; }
  else              { Bt = Wvt; C = vt; ldc = HKV_ * HD_; col0 = (bx - 20) * 128;
                      tv = true; }
  gemm_tile_f16<half_t>(xh, Bt, C, D_, ldc, by * 128, col0, tv, vt);
}

__global__ __launch_bounds__(256) void out_gemm_h(
    const half_t* __restrict__ attn, const half_t* __restrict__ Wot,
    float* __restrict__ out)
{
  // XCD 4x2-chunk swizzle (bijective, 512 = 8 * 64): each XCD owns 8x8.
  int lin = (int)blockIdx.y * 16 + (int)blockIdx.x;
  int xcd = lin & 7, idx = lin >> 3;           // idx in [0,64)
  int cy = xcd >> 1, cx = xcd & 1;
  int by = cy * 8 + idx / 8;
  int bx = cx * 8 + idx % 8;
  gemm_tile_f16<float>(attn, Wot, out, H_ * HD_, D_, by * 128, bx * 128,
                       false, nullptr);
}

// ---------------------------------------------------------------------------
// mid: blocks 0..255 build the RoPE trig table (into dead-after-qkv Wqt
// region; consumed by flash's fused q-norm); blocks 256.. do k-norm+RoPE.
// ---------------------------------------------------------------------------
__device__ __forceinline__ void norm_rope_row(
    half_t* __restrict__ buf, float wv, int row, int nheads, int lognh,
    int lane, float oscale, float cv, float sv)
{
  int head  = row & (nheads - 1);
  int token = row >> lognh;

  size_t idx = (size_t)token * (nheads * HD_) + head * HD_ + lane;
  float x = (float)buf[idx];

  float ss = x * x;
#pragma unroll
  for (int off = 32; off; off >>= 1) ss += __shfl_xor(ss, off);
  float xn = x * rsqrtf(ss * (1.0f / HD_) + EPS_) * wv;

  float partner = __shfl_xor(xn, 32);
  float res = (lane < 32) ? (xn * cv - partner * sv) : (xn * cv + partner * sv);
  buf[idx] = (half_t)(res * oscale);
}

__global__ __launch_bounds__(256) void mid(
    half_t* __restrict__ kh, const float* __restrict__ kw,
    float* __restrict__ ct, float* __restrict__ st)
{
  const int t = threadIdx.x;
  int id = blockIdx.x;

  if (id < 256) {            // trig table: 65536 entries = 2048 pos x 32
    int e = id * 256 + t;
    int l = e >> 5, fi = e & 31;
    float inv_freq = exp2f((float)fi * -0.622862853f);   // 1e6^(-2fi/64)
    float ang = (float)l * inv_freq;
    ct[e] = cosf(ang);
    st[e] = sinf(ang);
    return;
  }
  id -= 256;                 // k norm: 2048 blk x 4 waves x 4 rows = 32768 rows
  const int lane = t & 63;
  const int wv   = t >> 6;
  int fi = lane & 31;
  float inv_freq = exp2f((float)fi * -0.622862853f);
  int row0  = (id * 4 + wv) * 4;
  int token = row0 >> 3;                 // all 4 rows share one token
  int l     = token & (L_ - 1);          // RoPE position (batch masked out)
  float ang = (float)l * inv_freq;
  float cvv = cosf(ang), svv = sinf(ang);
  float wk  = kw[lane];
#pragma unroll
  for (int u = 0; u < 4; u++)
    norm_rope_row(kh, wk, row0 + u, HKV_, 3, lane, 1.0f, cvv, svv);
}

// ---------------------------------------------------------------------------
// MFMA flash attention (round-14 form — CONTROL this round).
// Fused q-norm/RoPE on Q-load; paired q-tiles; ones-MFMA row-sum; defer-max.
// ---------------------------------------------------------------------------
__global__ __launch_bounds__(512) void flash_mfma2(
    const half_t* __restrict__ Qh, const half_t* __restrict__ Kh,
    const half_t* __restrict__ Vt, half_t* __restrict__ Oa,
    const float* __restrict__ qw,
    const float* __restrict__ ct, const float* __restrict__ st)
{
  __shared__ __align__(16) half_t Ks[64][72];   // [k-token][d]
  __shared__ __align__(16) half_t Vs[64][72];   // [d][k-token]
  __shared__ __align__(16) half_t Ps[128][72];  // [q-local][k-local]
  __shared__ __align__(16) float  Ab[128];      // per-row alpha broadcast

  const int t    = threadIdx.x;
  const int w    = t >> 6;          // 0..7
  const int lane = t & 63;
  const int quad = lane >> 4;
  const int c    = lane & 15;
  const int h = blockIdx.y, b = blockIdx.z;
  const int kvh = h >> 2;

  const half_t* kbase = Kh + (size_t)(b * L_) * (HKV_ * HD_) + kvh * HD_;
  const half_t* vbase = Vt + (size_t)((b * HKV_ + kvh) * HD_) * L_;
  const int sr = t >> 3;            // 0..63
  const int su = (t & 7) * 8;       // 0..56 (halfs)

  half8_t ones;
#pragma unroll
  for (int u = 0; u < 8; u++) ones[u] = (half_t)1.0f;

  for (int pass = 0; pass < 2; pass++) {
    const int qb  = pass ? (15 - (int)blockIdx.x) : (int)blockIdx.x;
    const int q0  = qb * 128;
    const int wq0 = q0 + w * 16;    // this wave's first q row

    // Q fragments: fused RMS-norm + RoPE (table) on load
    half8_t qf0, qf1;
    {
      const half_t* qp = Qh + ((size_t)(b * L_ + wq0 + c)) * (H_ * HD_) + h * HD_;
      half8_t r0 = *(const half8_t*)&qp[quad * 8];
      half8_t r1 = *(const half8_t*)&qp[32 + quad * 8];
      float x1[8], x2[8];
      float ss = 0.f;
#pragma unroll
      for (int j = 0; j < 8; j++) {
        x1[j] = (float)r0[j]; x2[j] = (float)r1[j];
        ss += x1[j] * x1[j] + x2[j] * x2[j];
      }
      ss += __shfl_xor(ss, 16);
      ss += __shfl_xor(ss, 32);
      float rn = rsqrtf(ss * (1.0f / HD_) + EPS_);
      const int l = wq0 + c;                 // q position in [0, 2048)
      float4 c0 = *(const float4*)&ct[l * 32 + quad * 8];
      float4 c1 = *(const float4*)&ct[l * 32 + quad * 8 + 4];
      float4 s0 = *(const float4*)&st[l * 32 + quad * 8];
      float4 s1 = *(const float4*)&st[l * 32 + quad * 8 + 4];
      float4 w0 = *(const float4*)&qw[quad * 8];
      float4 w1 = *(const float4*)&qw[quad * 8 + 4];
      float4 w2 = *(const float4*)&qw[32 + quad * 8];
      float4 w3 = *(const float4*)&qw[32 + quad * 8 + 4];
      const float cs[8] = {c0.x, c0.y, c0.z, c0.w, c1.x, c1.y, c1.z, c1.w};
      const float sn[8] = {s0.x, s0.y, s0.z, s0.w, s1.x, s1.y, s1.z, s1.w};
      const float wa[8] = {w0.x, w0.y, w0.z, w0.w, w1.x, w1.y, w1.z, w1.w};
      const float wb[8] = {w2.x, w2.y, w2.z, w2.w, w3.x, w3.y, w3.z, w3.w};
#pragma unroll
      for (int j = 0; j < 8; j++) {
        float xa = x1[j] * rn * wa[j];
        float xb = x2[j] * rn * wb[j];
        qf0[j] = (half_t)((xa * cs[j] - xb * sn[j]) * 0.180336880f);
        qf1[j] = (half_t)((xb * cs[j] + xa * sn[j]) * 0.180336880f);
      }
    }

    float4_t o[5];                  // o[0..3] = O, o[4] = l (row-sum via ones-MFMA)
#pragma unroll
    for (int dt = 0; dt < 5; dt++) o[dt] = (float4_t){0.f, 0.f, 0.f, 0.f};
    float mm = -__builtin_inff();

    // prefetch tile 0 (one 16B chunk per thread for each of K, V)
    half8_t kr, vr;
    kr = *(const half8_t*)(kbase + (size_t)sr * (HKV_ * HD_) + su);
    vr = *(const half8_t*)(vbase + (size_t)sr * L_ + su);

    const int last = (q0 + 127) >> 6;
    for (int kt = 0; kt <= last; kt++) {
      const int kk0 = kt * 64;
      __syncthreads();
      *(half8_t*)&Ks[sr][su] = kr;
      *(half8_t*)&Vs[sr][su] = vr;
      __syncthreads();
      if (kt < last) {   // prefetch next tile while computing this one
        kr = *(const half8_t*)(kbase + (size_t)(kk0 + 64 + sr) * (HKV_ * HD_) + su);
        vr = *(const half8_t*)(vbase + (size_t)sr * L_ + kk0 + 64 + su);
      }
      if (kk0 > wq0 + 15) continue;   // tile fully above diagonal for this wave

      // S^T[k][q] = K Q^T : A = K frag, B = Q frag
      float4_t S[4];
      __builtin_amdgcn_s_setprio(1);
#pragma unroll
      for (int tt = 0; tt < 4; tt++) {
        half8_t kf0 = *(const half8_t*)&Ks[tt * 16 + c][quad * 8];
        half8_t kf1 = *(const half8_t*)&Ks[tt * 16 + c][32 + quad * 8];
        float4_t s = (float4_t){0.f, 0.f, 0.f, 0.f};
        s = __builtin_amdgcn_mfma_f32_16x16x32_f16(kf0, qf0, s, 0, 0, 0);
        s = __builtin_amdgcn_mfma_f32_16x16x32_f16(kf1, qf1, s, 0, 0, 0);
        S[tt] = s;
      }
      __builtin_amdgcn_s_setprio(0);

      // causal mask (only near-diagonal tiles)
      if (kk0 + 63 > wq0) {
#pragma unroll
        for (int tt = 0; tt < 4; tt++) {
          int base = kk0 + tt * 16 + quad * 4 - (wq0 + c);
#pragma unroll
          for (int r = 0; r < 4; r++)
            if (base + r > 0) S[tt][r] = -__builtin_inff();
        }
      }

      // online softmax (exp2 domain), defer-max THR=8
      {
        float4_t m4 = fmax4(fmax4(S[0], S[1]), fmax4(S[2], S[3]));
        float mloc = fmaxf(fmaxf(m4[0], m4[1]), fmaxf(m4[2], m4[3]));
        mloc = fmaxf(mloc, __shfl_xor(mloc, 16));
        mloc = fmaxf(mloc, __shfl_xor(mloc, 32));
        if (__any(mloc > mm + 8.0f)) {       // wave-uniform rescale (rare)
          float mnew = fmaxf(mm, mloc);
          float al = exp2f(mm - mnew);
          mm = mnew;
          if (quad == 0) Ab[w * 16 + c] = al;
          float4_t av = *(const float4_t*)&Ab[w * 16 + quad * 4];
#pragma unroll
          for (int dt = 0; dt < 5; dt++)
#pragma unroll
            for (int r = 0; r < 4; r++) o[dt][r] *= av[r];
        }
#pragma unroll
        for (int tt = 0; tt < 4; tt++) {
#pragma unroll
          for (int r = 0; r < 4; r++) S[tt][r] = exp2f(S[tt][r] - mm);
          uint2 pw;
          pw.x = pk_f16(S[tt][0], S[tt][1]);
          pw.y = pk_f16(S[tt][2], S[tt][3]);
          *(uint2*)&Ps[w * 16 + c][tt * 16 + quad * 4] = pw;
        }
      }

      // O += P V ; l += P 1 (ones-MFMA)
      half8_t pf0 = *(const half8_t*)&Ps[w * 16 + c][quad * 8];
      half8_t pf1 = *(const half8_t*)&Ps[w * 16 + c][32 + quad * 8];
      __builtin_amdgcn_s_setprio(1);
      o[4] = __builtin_amdgcn_mfma_f32_16x16x32_f16(pf0, ones, o[4], 0, 0, 0);
      o[4] = __builtin_amdgcn_mfma_f32_16x16x32_f16(pf1, ones, o[4], 0, 0, 0);
#pragma unroll
      for (int dt = 0; dt < 4; dt++) {
        half8_t vf0 = *(const half8_t*)&Vs[dt * 16 + c][quad * 8];
        half8_t vf1 = *(const half8_t*)&Vs[dt * 16 + c][32 + quad * 8];
        o[dt] = __builtin_amdgcn_mfma_f32_16x16x32_f16(pf0, vf0, o[dt], 0, 0, 0);
        o[dt] = __builtin_amdgcn_mfma_f32_16x16x32_f16(pf1, vf1, o[dt], 0, 0, 0);
      }
      __builtin_amdgcn_s_setprio(0);
    }

    // epilogue: normalize by l (= o[4], same row layout), store
#pragma unroll
    for (int r = 0; r < 4; r++) {
      float inv = 1.0f / o[4][r];
      half_t* op = Oa + ((size_t)(b * L_ + wq0 + quad * 4 + r)) * (H_ * HD_)
                 + h * HD_ + c;
#pragma unroll
      for (int dt = 0; dt < 4; dt++)
        op[dt * 16] = (half_t)(o[dt][r] * inv);
    }
  }
}

// ---------------------------------------------------------------------------
extern "C" void kernel_launch(void* const* d_in, const int* in_sizes, int n_in,
                              void* d_out, int out_size, void* d_ws, size_t ws_size,
                              hipStream_t stream)
{
  const float* x  = (const float*)d_in[0];
  const float* Wq = (const float*)d_in[1];
  const float* Wk = (const float*)d_in[2];
  const float* Wv = (const float*)d_in[3];
  const float* Wo = (const float*)d_in[4];
  const float* qw = (const float*)d_in[5];
  const float* kw = (const float*)d_in[6];
  float* out = (float*)d_out;

  const size_t XN = (size_t)B_ * L_ * D_;          // 8M
  const size_t QN = (size_t)B_ * L_ * H_ * HD_;    // 8M
  const size_t KN = (size_t)B_ * L_ * HKV_ * HD_;  // 2M
  const size_t WQ = (size_t)D_ * H_ * HD_;         // 4M
  const size_t WK = (size_t)D_ * HKV_ * HD_;       // 1M

  half_t* p   = (half_t*)d_ws;
  half_t* xh  = p;  p += XN;   // reused as attn output
  half_t* Wqt = p;  p += WQ;
  half_t* Wkt = p;  p += WK;
  half_t* Wvt = p;  p += WK;
  half_t* Wot = p;  p += WQ;
  half_t* qh  = p;  p += QN;
  half_t* kh  = p;  p += KN;
  half_t* vt  = p;  p += KN;   // written DIRECTLY transposed by qkv_gemm_h
  half_t* attn = xh;           // xh dead after qkv_gemm_h

  // trig table overlays the Wqt region (dead after qkv_gemm_h); consumed by
  // flash's fused q-norm.
  float* ct = (float*)Wqt;     // 65536 floats
  float* st = ct + 65536;      // 65536 floats (512KB total << 8MB region)

  // 0) fused conversions + weight transposes
  prep_all<<<6656, 256, 0, stream>>>(x, Wq, Wk, Wv, Wo, xh, Wqt, Wkt, Wvt, Wot);

  // 1) QKV projections (2-phase dbuf pipeline, XCD swizzle; v direct-transposed)
  qkv_gemm_h<<<dim3(24, 32), 256, 0, stream>>>(xh, Wqt, Wkt, Wvt, qh, kh, vt);

  // 2) trig table (into dead Wqt region) + k-norm/RoPE, one launch
  mid<<<256 + 2048, 256, 0, stream>>>(kh, kw, ct, st);

  // 3) MFMA flash attention with fused q-norm/RoPE on Q-load (control)
  flash_mfma2<<<dim3(8, H_, B_), 512, 0, stream>>>(qh, kh, vt, attn, qw, ct, st);

  // 4) output projection (2-phase dbuf pipeline, XCD swizzle)
  out_gemm_h<<<dim3(16, 32), 256, 0, stream>>>(attn, Wot, out);
}